// Round 5
// baseline (264.067 us; speedup 1.0000x reference)
//
#include <hip/hip_runtime.h>
#include <math.h>
#include <stdint.h>

// Problem constants (B=16, I=256, T=8192), x float32, out float32
#define T_LEN 8192
#define NSTEP 8189   // T-3 sampled steps
#define NB 16
#define NI 256
#define OUTT 8190    // T-2 output time length
#define CHUNK 128
#define NCHUNK 64    // 64*128 = 8192 >= NSTEP

// gather grid: two half-dispatches (A/B experiment: nt store vs plain store)
// total 4-float tiles = 16*256*8190/4 = 8,386,560; half = 4,193,280
//   = 1638 blocks * 256 threads * 10 iters exactly.
// Halfway flat index 16,773,120 = 2048*8190: exact row boundary (row 2048),
// and no tile crosses it (row 2047 is odd -> its tiles end at j=8190).
#define G_BLOCKS 1638
#define G_THREADS 256
#define G_STRIDE (G_BLOCKS * G_THREADS)   // 419328
#define G_ITERS 10
#define HALF_TILES 4193280u

// native vector types for nontemporal builtins (HIP_vector_type not accepted)
typedef float f32x4 __attribute__((ext_vector_type(4)));

// ---------------- threefry2x32 (JAX-compatible, 20 rounds) ----------------
__device__ __forceinline__ uint32_t rotl32(uint32_t v, int r) {
  return (v << r) | (v >> (32 - r));
}

__device__ __forceinline__ void tf2x32(uint32_t k0, uint32_t k1,
                                       uint32_t x0, uint32_t x1,
                                       uint32_t& o0, uint32_t& o1) {
  uint32_t k2 = k0 ^ k1 ^ 0x1BD11BDAu;
  x0 += k0; x1 += k1;
  // group 1 (rot set A: 13,15,26,6)
  x0 += x1; x1 = rotl32(x1, 13); x1 ^= x0;
  x0 += x1; x1 = rotl32(x1, 15); x1 ^= x0;
  x0 += x1; x1 = rotl32(x1, 26); x1 ^= x0;
  x0 += x1; x1 = rotl32(x1,  6); x1 ^= x0;
  x0 += k1; x1 += k2 + 1u;
  // group 2 (rot set B: 17,29,16,24)
  x0 += x1; x1 = rotl32(x1, 17); x1 ^= x0;
  x0 += x1; x1 = rotl32(x1, 29); x1 ^= x0;
  x0 += x1; x1 = rotl32(x1, 16); x1 ^= x0;
  x0 += x1; x1 = rotl32(x1, 24); x1 ^= x0;
  x0 += k2; x1 += k0 + 2u;
  // group 3 (A)
  x0 += x1; x1 = rotl32(x1, 13); x1 ^= x0;
  x0 += x1; x1 = rotl32(x1, 15); x1 ^= x0;
  x0 += x1; x1 = rotl32(x1, 26); x1 ^= x0;
  x0 += x1; x1 = rotl32(x1,  6); x1 ^= x0;
  x0 += k0; x1 += k1 + 3u;
  // group 4 (B)
  x0 += x1; x1 = rotl32(x1, 17); x1 ^= x0;
  x0 += x1; x1 = rotl32(x1, 29); x1 ^= x0;
  x0 += x1; x1 = rotl32(x1, 16); x1 ^= x0;
  x0 += x1; x1 = rotl32(x1, 24); x1 ^= x0;
  x0 += k1; x1 += k2 + 4u;
  // group 5 (A)
  x0 += x1; x1 = rotl32(x1, 13); x1 ^= x0;
  x0 += x1; x1 = rotl32(x1, 15); x1 ^= x0;
  x0 += x1; x1 = rotl32(x1, 26); x1 ^= x0;
  x0 += x1; x1 = rotl32(x1,  6); x1 ^= x0;
  x0 += k2; x1 += k0 + 5u;
  o0 = x0; o1 = x1;
}

// Correctly-rounded float32 log via double precision (validated bit-exact vs ref)
__device__ __forceinline__ float f32log_cr(float x) {
  return (float)log((double)x);
}

// jax uniform(minval=tiny,maxval=1) -> gumbel, exact f32 semantics (validated)
__device__ __forceinline__ float bits_to_gumbel(uint32_t bits) {
  uint32_t fb = (bits >> 9) | 0x3F800000u;
  float u = __uint_as_float(fb) - 1.0f;           // exact, in [0, 1)
  if (u == 0.0f) u = 1.17549435e-38f;             // finfo(f32).tiny
  float inner = f32log_cr(u);                     // < 0
  float outer = f32log_cr(-inner);
  return -outer;
}

__device__ __forceinline__ int chain_step(int sigma, uint32_t dv) {
  int s = (sigma == 5) ? (int)(dv >> 2) : (int)(dv & 3u);
  return (sigma % 3) * 3 + s;
}

// -------- Kernel 1 (fused): decision bytes + per-chunk 9-state maps --------
// Decision math byte-identical to the validated round-2/3 kernel.
__global__ void k_dec_spec(const int* __restrict__ seedp,
                           uint8_t* __restrict__ dec,
                           uint8_t* __restrict__ Mend) {
  __shared__ uint8_t ld[CHUNK];
  int c = blockIdx.x, b = blockIdx.y;
  int t = c * CHUNK + threadIdx.x;

  if (t < NSTEP) {
    uint32_t sk0 = 0u;                      // threefry_seed(int32): hi word 0
    uint32_t sk1 = (uint32_t)seedp[0];
    uint32_t kt0, kt1;
    tf2x32(sk0, sk1, 0u, (uint32_t)t, kt0, kt1);  // split key for step t

    float g[3];
#pragma unroll
    for (int e = 0; e < 3; ++e) {
      uint32_t o0, o1;
      tf2x32(kt0, kt1, 0u, (uint32_t)(3 * b + e), o0, o1);
      g[e] = bits_to_gumbel(o0 ^ o1);
    }

    const double pd = 0.1;
    const double sd = 1.0 - 2.0 * 0.1;
    const float Lp  = f32log_cr((float)pd);
    const float Ls  = f32log_cr((float)sd);
    const float Lb1 = f32log_cr((float)(sd / (pd + sd)));
    const float Lb2 = f32log_cr((float)(pd / (pd + sd)));

    float z0 = g[0] + Lp, z1 = g[1] + Ls, z2 = g[2] + Lp;
    int an = 0; float best = z0;
    if (z1 > best) { best = z1; an = 1; }
    if (z2 > best) { an = 2; }
    int as_ = ((g[2] + Lb2) > (g[1] + Lb1)) ? 2 : 1;

    uint8_t v = (uint8_t)(an | (as_ << 2));
    ld[threadIdx.x] = v;
    dec[b * T_LEN + t] = v;
  }
  __syncthreads();

  if (threadIdx.x < 9) {
    int sigma = threadIdx.x;
    int n = min(CHUNK, NSTEP - c * CHUNK);
    for (int k = 0; k < n; ++k) sigma = chain_step(sigma, ld[k]);
    Mend[(b * NCHUNK + c) * 9 + threadIdx.x] = (uint8_t)sigma;
  }
}

// -------- Kernel 2 (fused): fold chunk maps + apply -> st2 -----------------
__global__ void k_chain(const uint8_t* __restrict__ dec,
                        const uint8_t* __restrict__ Mend,
                        uint8_t* __restrict__ st2) {
  __shared__ uint8_t m[NCHUNK * 9];
  __shared__ uint8_t entry[NCHUNK];
  int b = blockIdx.x;
  for (int idx = threadIdx.x; idx < NCHUNK * 9; idx += blockDim.x)
    m[idx] = Mend[b * NCHUNK * 9 + idx];
  __syncthreads();
  if (threadIdx.x == 0) {
    int sigma = 4;  // (prev2,prev1) = (1,1)
    for (int cc = 0; cc < NCHUNK; ++cc) {
      entry[cc] = (uint8_t)sigma;
      sigma = m[cc * 9 + sigma];
    }
  }
  __syncthreads();
  int c = threadIdx.x;
  int t0 = c * CHUNK;
  int sigma = entry[c];
  const uint32_t* dw = (const uint32_t*)(dec + b * T_LEN + t0);  // 4-aligned
  uint8_t* s2 = st2 + b * T_LEN;
  if (c == 0) s2[0] = 1;  // st[1] = 1 -> st2[0]
#pragma unroll 8
  for (int wi = 0; wi < CHUNK / 4; ++wi) {
    uint32_t word = dw[wi];
#pragma unroll
    for (int r = 0; r < 4; ++r) {
      int t = t0 + 4 * wi + r;
      uint32_t dv = (word >> (8 * r)) & 0xFFu;
      int s = (sigma == 5) ? (int)(dv >> 2) : (int)(dv & 3u);
      if (t < NSTEP) s2[t + 1] = (uint8_t)s;  // guard: don't stomp next batch's st2[0]
      sigma = (sigma % 3) * 3 + s;
    }
  }
}

// -------- Kernel 3: half-range gather, templated store flavor --------------
// Same validated flat-output tile body (round 3/4, absmax=0). Two dispatches
// with disjoint row halves (rows 0..2047 / 2048..4095); template<NT> selects
// nontemporal vs plain store. A/B experiment: on gfx9 vmcnt counts loads AND
// stores in issue order, so the per-iteration s_waitcnt before using the next
// loads also waits on the previous store's completion. Theory: nt stores only
// retire at the memory side (~900+cy + queue) instead of L2 (~200cy),
// serializing every grid-stride iteration on an HBM write round-trip ->
// the invariant 82us/2.5TB/s across all structures since round 2.
template <int NT>
__global__ void __launch_bounds__(256) k_gather_h(const float* __restrict__ x,
                                                  const uint8_t* __restrict__ st2,
                                                  float* __restrict__ out,
                                                  uint32_t gbase) {
  uint32_t g0 = gbase + blockIdx.x * (uint32_t)G_THREADS + threadIdx.x;
#pragma unroll 4
  for (int it = 0; it < G_ITERS; ++it) {
    uint32_t g = g0 + (uint32_t)it * (uint32_t)G_STRIDE;
    uint32_t f = g * 4u;                          // flat out index, %4==0
    uint32_t row = f / 8190u;                     // magic-mul division
    uint32_t j = f - row * 8190u;                 // j%4 == 2*(row&1)
    uint32_t b = row >> 8;
    const float* xr = x + (size_t)row * (size_t)T_LEN;
    const uint8_t* sp = st2 + (size_t)b * (size_t)T_LEN;

    f32x4 r;
    if (j <= 8186u) {                             // tile within one row
      float res[4];
      if ((row & 1u) == 0u) {                     // even row: j%4 == 0
        uint32_t J = j;
        float4 A  = *(const float4*)(xr + J);     // x[J..J+3]
        float4 Bv = *(const float4*)(xr + J + 4); // x[J+4..J+7]
        uint32_t s0 = *(const uint32_t*)(sp + J); // st2[J..J+3]
        float w[8] = {A.x, A.y, A.z, A.w, Bv.x, Bv.y, Bv.z, Bv.w};
#pragma unroll
        for (int m = 0; m < 4; ++m) {
          uint32_t s = (s0 >> (8 * m)) & 0xFFu;
          res[m] = (s == 0) ? w[m] : ((s == 1) ? w[m + 1] : w[m + 2]);
        }
      } else {                                    // odd row: j%4 == 2
        uint32_t J = j - 2u;                      // J%4 == 0
        float4 A  = *(const float4*)(xr + J);     // x[j-2..j+1]
        float4 Bv = *(const float4*)(xr + J + 4); // x[j+2..j+5]
        uint32_t s0 = *(const uint32_t*)(sp + J);     // st2[j-2..j+1]
        uint32_t s1 = *(const uint32_t*)(sp + J + 4); // st2[j+2..j+5]
        float w[8] = {A.x, A.y, A.z, A.w, Bv.x, Bv.y, Bv.z, Bv.w};
        uint32_t sb[4] = { (s0 >> 16) & 0xFFu, s0 >> 24,
                           s1 & 0xFFu, (s1 >> 8) & 0xFFu };  // st2[j..j+3]
#pragma unroll
        for (int m = 0; m < 4; ++m) {
          uint32_t s = sb[m];
          res[m] = (s == 0) ? w[m + 2] : ((s == 1) ? w[m + 3] : w[m + 4]);
        }
      }
      r = f32x4{ res[0], res[1], res[2], res[3] };
    } else {
      // row-crossing tile: even row r at j=8188 -> outs r[8188], r[8189],
      // (r+1)[0], (r+1)[1]; r+1 same batch, and never crosses the half split
      // (crossings only start at even rows; half boundary row 2048 is
      // preceded by odd row 2047 whose tiles end exactly at the boundary).
      float4 A  = *(const float4*)(xr + 8188);    // x[r][8188..8191]
      uint32_t s0 = *(const uint32_t*)(sp + 8188);
      uint32_t b0 = s0 & 0xFFu, b1 = (s0 >> 8) & 0xFFu;
      float r0 = (b0 == 0) ? A.x : ((b0 == 1) ? A.y : A.z);
      float r1 = (b1 == 0) ? A.y : ((b1 == 1) ? A.z : A.w);
      const float* xr2 = xr + T_LEN;              // row r+1
      float4 A2 = *(const float4*)(xr2);          // x[r+1][0..3]
      uint32_t q0 = *(const uint32_t*)(sp);       // st2[0..3]
      uint32_t c0 = q0 & 0xFFu, c1 = (q0 >> 8) & 0xFFu;
      float r2 = (c0 == 0) ? A2.x : ((c0 == 1) ? A2.y : A2.z);
      float r3 = (c1 == 0) ? A2.y : ((c1 == 1) ? A2.z : A2.w);
      r = f32x4{ r0, r1, r2, r3 };
    }
    if (NT) {
      __builtin_nontemporal_store(r, (f32x4*)(out + f));
    } else {
      *(f32x4*)(out + f) = r;
    }
  }
}

extern "C" void kernel_launch(void* const* d_in, const int* in_sizes, int n_in,
                              void* d_out, int out_size, void* d_ws, size_t ws_size,
                              hipStream_t stream) {
  const float* x   = (const float*)d_in[0];   // float32 input
  const int* seedp = (const int*)d_in[1];
  float* out       = (float*)d_out;           // float32 output

  uint8_t* ws    = (uint8_t*)d_ws;
  uint8_t* dec   = ws;                        // 16*8192 = 131072 B
  uint8_t* st2   = dec + NB * T_LEN;          // 131072 B
  uint8_t* Mend  = st2 + NB * T_LEN;          // 16*64*9 = 9216 B

  k_dec_spec<<<dim3(NCHUNK, NB), CHUNK, 0, stream>>>(seedp, dec, Mend);
  k_chain<<<NB, NCHUNK, 0, stream>>>(dec, Mend, st2);
  // A/B: half 0 (rows 0..2047) with nt stores, half 1 (rows 2048..4095)
  // with plain stores. Identical body otherwise; disjoint working sets.
  k_gather_h<1><<<dim3(G_BLOCKS), G_THREADS, 0, stream>>>(x, st2, out, 0u);
  k_gather_h<0><<<dim3(G_BLOCKS), G_THREADS, 0, stream>>>(x, st2, out, HALF_TILES);
}

// Round 6
// 249.290 us; speedup vs baseline: 1.0593x; 1.0593x over previous
//
#include <hip/hip_runtime.h>
#include <math.h>
#include <stdint.h>

// Problem constants (B=16, I=256, T=8192), x float32, out float32
#define T_LEN 8192
#define NSTEP 8189   // T-3 sampled steps
#define NB 16
#define NI 256
#define OUTT 8190    // T-2 output time length
#define CHUNK 128
#define NCHUNK 64    // 64*128 = 8192 >= NSTEP

// native vector types for nontemporal builtins (HIP_vector_type not accepted)
typedef float f32x4 __attribute__((ext_vector_type(4)));

// ---------------- threefry2x32 (JAX-compatible, 20 rounds) ----------------
__device__ __forceinline__ uint32_t rotl32(uint32_t v, int r) {
  return (v << r) | (v >> (32 - r));
}

__device__ __forceinline__ void tf2x32(uint32_t k0, uint32_t k1,
                                       uint32_t x0, uint32_t x1,
                                       uint32_t& o0, uint32_t& o1) {
  uint32_t k2 = k0 ^ k1 ^ 0x1BD11BDAu;
  x0 += k0; x1 += k1;
  // group 1 (rot set A: 13,15,26,6)
  x0 += x1; x1 = rotl32(x1, 13); x1 ^= x0;
  x0 += x1; x1 = rotl32(x1, 15); x1 ^= x0;
  x0 += x1; x1 = rotl32(x1, 26); x1 ^= x0;
  x0 += x1; x1 = rotl32(x1,  6); x1 ^= x0;
  x0 += k1; x1 += k2 + 1u;
  // group 2 (rot set B: 17,29,16,24)
  x0 += x1; x1 = rotl32(x1, 17); x1 ^= x0;
  x0 += x1; x1 = rotl32(x1, 29); x1 ^= x0;
  x0 += x1; x1 = rotl32(x1, 16); x1 ^= x0;
  x0 += x1; x1 = rotl32(x1, 24); x1 ^= x0;
  x0 += k2; x1 += k0 + 2u;
  // group 3 (A)
  x0 += x1; x1 = rotl32(x1, 13); x1 ^= x0;
  x0 += x1; x1 = rotl32(x1, 15); x1 ^= x0;
  x0 += x1; x1 = rotl32(x1, 26); x1 ^= x0;
  x0 += x1; x1 = rotl32(x1,  6); x1 ^= x0;
  x0 += k0; x1 += k1 + 3u;
  // group 4 (B)
  x0 += x1; x1 = rotl32(x1, 17); x1 ^= x0;
  x0 += x1; x1 = rotl32(x1, 29); x1 ^= x0;
  x0 += x1; x1 = rotl32(x1, 16); x1 ^= x0;
  x0 += x1; x1 = rotl32(x1, 24); x1 ^= x0;
  x0 += k1; x1 += k2 + 4u;
  // group 5 (A)
  x0 += x1; x1 = rotl32(x1, 13); x1 ^= x0;
  x0 += x1; x1 = rotl32(x1, 15); x1 ^= x0;
  x0 += x1; x1 = rotl32(x1, 26); x1 ^= x0;
  x0 += x1; x1 = rotl32(x1,  6); x1 ^= x0;
  x0 += k2; x1 += k0 + 5u;
  o0 = x0; o1 = x1;
}

// Correctly-rounded float32 log via double precision (validated bit-exact vs ref)
__device__ __forceinline__ float f32log_cr(float x) {
  return (float)log((double)x);
}

// jax uniform(minval=tiny,maxval=1) -> gumbel, exact f32 semantics (validated)
__device__ __forceinline__ float bits_to_gumbel(uint32_t bits) {
  uint32_t fb = (bits >> 9) | 0x3F800000u;
  float u = __uint_as_float(fb) - 1.0f;           // exact, in [0, 1)
  if (u == 0.0f) u = 1.17549435e-38f;             // finfo(f32).tiny
  float inner = f32log_cr(u);                     // < 0
  float outer = f32log_cr(-inner);
  return -outer;
}

__device__ __forceinline__ int chain_step(int sigma, uint32_t dv) {
  int s = (sigma == 5) ? (int)(dv >> 2) : (int)(dv & 3u);
  return (sigma % 3) * 3 + s;
}

// -------- Kernel 1 (fused): decision bytes + per-chunk 9-state maps --------
// Decision math byte-identical to the validated round-2/3 kernel.
__global__ void k_dec_spec(const int* __restrict__ seedp,
                           uint8_t* __restrict__ dec,
                           uint8_t* __restrict__ Mend) {
  __shared__ uint8_t ld[CHUNK];
  int c = blockIdx.x, b = blockIdx.y;
  int t = c * CHUNK + threadIdx.x;

  if (t < NSTEP) {
    uint32_t sk0 = 0u;                      // threefry_seed(int32): hi word 0
    uint32_t sk1 = (uint32_t)seedp[0];
    uint32_t kt0, kt1;
    tf2x32(sk0, sk1, 0u, (uint32_t)t, kt0, kt1);  // split key for step t

    float g[3];
#pragma unroll
    for (int e = 0; e < 3; ++e) {
      uint32_t o0, o1;
      tf2x32(kt0, kt1, 0u, (uint32_t)(3 * b + e), o0, o1);
      g[e] = bits_to_gumbel(o0 ^ o1);
    }

    const double pd = 0.1;
    const double sd = 1.0 - 2.0 * 0.1;
    const float Lp  = f32log_cr((float)pd);
    const float Ls  = f32log_cr((float)sd);
    const float Lb1 = f32log_cr((float)(sd / (pd + sd)));
    const float Lb2 = f32log_cr((float)(pd / (pd + sd)));

    float z0 = g[0] + Lp, z1 = g[1] + Ls, z2 = g[2] + Lp;
    int an = 0; float best = z0;
    if (z1 > best) { best = z1; an = 1; }
    if (z2 > best) { an = 2; }
    int as_ = ((g[2] + Lb2) > (g[1] + Lb1)) ? 2 : 1;

    uint8_t v = (uint8_t)(an | (as_ << 2));
    ld[threadIdx.x] = v;
    dec[b * T_LEN + t] = v;
  }
  __syncthreads();

  if (threadIdx.x < 9) {
    int sigma = threadIdx.x;
    int n = min(CHUNK, NSTEP - c * CHUNK);
    for (int k = 0; k < n; ++k) sigma = chain_step(sigma, ld[k]);
    Mend[(b * NCHUNK + c) * 9 + threadIdx.x] = (uint8_t)sigma;
  }
}

// -------- Kernel 2 (fused): fold chunk maps + apply -> st2 -----------------
__global__ void k_chain(const uint8_t* __restrict__ dec,
                        const uint8_t* __restrict__ Mend,
                        uint8_t* __restrict__ st2) {
  __shared__ uint8_t m[NCHUNK * 9];
  __shared__ uint8_t entry[NCHUNK];
  int b = blockIdx.x;
  for (int idx = threadIdx.x; idx < NCHUNK * 9; idx += blockDim.x)
    m[idx] = Mend[b * NCHUNK * 9 + idx];
  __syncthreads();
  if (threadIdx.x == 0) {
    int sigma = 4;  // (prev2,prev1) = (1,1)
    for (int cc = 0; cc < NCHUNK; ++cc) {
      entry[cc] = (uint8_t)sigma;
      sigma = m[cc * 9 + sigma];
    }
  }
  __syncthreads();
  int c = threadIdx.x;
  int t0 = c * CHUNK;
  int sigma = entry[c];
  const uint32_t* dw = (const uint32_t*)(dec + b * T_LEN + t0);  // 4-aligned
  uint8_t* s2 = st2 + b * T_LEN;
  if (c == 0) s2[0] = 1;  // st[1] = 1 -> st2[0]
#pragma unroll 8
  for (int wi = 0; wi < CHUNK / 4; ++wi) {
    uint32_t word = dw[wi];
#pragma unroll
    for (int r = 0; r < 4; ++r) {
      int t = t0 + 4 * wi + r;
      uint32_t dv = (word >> (8 * r)) & 0xFFu;
      int s = (sigma == 5) ? (int)(dv >> 2) : (int)(dv & 3u);
      if (t < NSTEP) s2[t + 1] = (uint8_t)s;  // guard: don't stomp next batch's st2[0]
      sigma = (sigma % 3) * 3 + s;
    }
  }
}

// -------- Kernel 3: shfl-window flat-output gather -------------------------
// One-shot grid (round-3 structure: fastest measured), flat out index, one
// aligned f32x4 nt store per thread. READ-PATH CHANGE vs round 3: the second
// float4 load (x[J+4..J+7], 15/16 duplicate cache lines of load A) and the
// second st2 word are replaced by cross-lane shuffles -- lane l+1's A
// register IS x[J+4..J+7] for lane l (consecutive lanes, J pitch 4 floats).
// Only lanes whose successor tile lies in a different row keep a real load:
// lane 63 of each wave, and odd-row last tiles (J==8184). ~2 lanes/wave,
// exec-masked. A-loads and shuffles are hoisted above all branches so every
// lane (incl. the rare row-crossing tile, which uses J=8188 and loads its
// own second row) is a valid shuffle source. Cuts per-wave read-path line
// lookups ~34 -> ~18 and VMEM wave-ops ~4.5 -> ~2.5 per tile, removing all
// duplicate-line L1/MSHR pressure (theory: that duplication is why three
// structurally different gathers all pinned at ~2.5 TB/s while the m13 copy
// -- same store stream, single lane-pitch-16B load stream -- does 6.3).
__global__ void __launch_bounds__(256) k_gather(const float* __restrict__ x,
                                                const uint8_t* __restrict__ st2,
                                                float* __restrict__ out) {
  uint32_t g = blockIdx.x * 256u + threadIdx.x;   // 0..8386559
  uint32_t f = g * 4u;                            // flat out index, %4==0
  uint32_t row = f / 8190u;                       // magic-mul division
  uint32_t j = f - row * 8190u;                   // j%4 == 2*(row&1)
  uint32_t b = row >> 8;
  bool odd = (row & 1u) != 0u;
  bool cross = (j > 8186u);                       // j==8188, even row only
  uint32_t J = cross ? 8188u : (odd ? j - 2u : j);  // J%4 == 0 always
  const float* xr = x + (size_t)row * (size_t)T_LEN;
  const uint8_t* sp = st2 + (size_t)b * (size_t)T_LEN;

  // unconditional: one aligned float4 + one aligned word per lane
  float4 A = *(const float4*)(xr + J);            // x[J..J+3]
  uint32_t s0 = *(const uint32_t*)(sp + J);       // st2[J..J+3]

  // lanes whose successor tile is in a different row load their own tail
  bool needB = !cross && (((threadIdx.x & 63u) == 63u) || (odd && J == 8184u));
  float4 Bv = make_float4(0.f, 0.f, 0.f, 0.f);
  uint32_t s1 = 0u;
  if (needB) {
    Bv = *(const float4*)(xr + J + 4);            // x[J+4..J+7] (in-row)
    s1 = *(const uint32_t*)(sp + J + 4);
  }

  // cross-lane window: lane l+1's A = x[J+4..J+7] of lane l (all lanes
  // active here -> valid shuffle sources)
  float n0 = __shfl_down(A.x, 1);
  float n1 = __shfl_down(A.y, 1);
  float n2 = __shfl_down(A.z, 1);
  float n3 = __shfl_down(A.w, 1);
  uint32_t ns = __shfl_down(s0, 1);
  if (!needB) { Bv = make_float4(n0, n1, n2, n3); s1 = ns; }

  if (!cross) {
    float w[8] = {A.x, A.y, A.z, A.w, Bv.x, Bv.y, Bv.z, Bv.w};
    float res[4];
    if (!odd) {                                   // even row: j%4 == 0
#pragma unroll
      for (int m = 0; m < 4; ++m) {
        uint32_t s = (s0 >> (8 * m)) & 0xFFu;     // st2[j..j+3]
        res[m] = (s == 0) ? w[m] : ((s == 1) ? w[m + 1] : w[m + 2]);
      }
    } else {                                      // odd row: j%4 == 2
      uint32_t sb[4] = { (s0 >> 16) & 0xFFu, s0 >> 24,
                         s1 & 0xFFu, (s1 >> 8) & 0xFFu };  // st2[j..j+3]
#pragma unroll
      for (int m = 0; m < 4; ++m) {
        uint32_t s = sb[m];
        res[m] = (s == 0) ? w[m + 2] : ((s == 1) ? w[m + 3] : w[m + 4]);
      }
    }
    f32x4 r = { res[0], res[1], res[2], res[3] };
    __builtin_nontemporal_store(r, (f32x4*)(out + f));
  } else {
    // row-crossing tile: even row r at j=8188 -> outs r[8188], r[8189],
    // (r+1)[0], (r+1)[1]; r+1 same batch (i = row&255 <= 254).
    // A = x[r][8188..8191], s0 = st2[8188..8191] (loaded above, J=8188).
    uint32_t b0 = s0 & 0xFFu, b1 = (s0 >> 8) & 0xFFu;
    float r0 = (b0 == 0) ? A.x : ((b0 == 1) ? A.y : A.z);
    float r1 = (b1 == 0) ? A.y : ((b1 == 1) ? A.z : A.w);
    const float* xr2 = xr + T_LEN;                // row r+1
    float4 A2 = *(const float4*)(xr2);            // x[r+1][0..3]
    uint32_t q0 = *(const uint32_t*)(sp);         // st2[0..3]
    uint32_t c0 = q0 & 0xFFu, c1 = (q0 >> 8) & 0xFFu;
    float r2 = (c0 == 0) ? A2.x : ((c0 == 1) ? A2.y : A2.z);
    float r3 = (c1 == 0) ? A2.y : ((c1 == 1) ? A2.z : A2.w);
    f32x4 r = { r0, r1, r2, r3 };
    __builtin_nontemporal_store(r, (f32x4*)(out + f));
  }
}

extern "C" void kernel_launch(void* const* d_in, const int* in_sizes, int n_in,
                              void* d_out, int out_size, void* d_ws, size_t ws_size,
                              hipStream_t stream) {
  const float* x   = (const float*)d_in[0];   // float32 input
  const int* seedp = (const int*)d_in[1];
  float* out       = (float*)d_out;           // float32 output

  uint8_t* ws    = (uint8_t*)d_ws;
  uint8_t* dec   = ws;                        // 16*8192 = 131072 B
  uint8_t* st2   = dec + NB * T_LEN;          // 131072 B
  uint8_t* Mend  = st2 + NB * T_LEN;          // 16*64*9 = 9216 B

  k_dec_spec<<<dim3(NCHUNK, NB), CHUNK, 0, stream>>>(seedp, dec, Mend);
  k_chain<<<NB, NCHUNK, 0, stream>>>(dec, Mend, st2);
  // flat out: 33,546,240 floats = 32760 blocks * 256 threads * 4 floats
  k_gather<<<dim3(32760), 256, 0, stream>>>(x, st2, out);
}